// Round 2
// baseline (1841.687 us; speedup 1.0000x reference)
//
#include <hip/hip_runtime.h>

#define DIM 1024
#define NKN 65536
#define TOK 4096
#define CK 20
#define FK 10
#define RNK 128
#define CAP 256
#define NCHUNK 512   // 65536 / 128 cols per GEMM block

typedef __bf16 v8bf __attribute__((ext_vector_type(8)));
typedef float v4f __attribute__((ext_vector_type(4)));

#define AS1 __attribute__((address_space(1)))
#define AS3 __attribute__((address_space(3)))

__device__ __forceinline__ unsigned short f2bf(float f) {
  // round-to-nearest-even fp32 -> bf16 (finite inputs only)
  unsigned u = __builtin_bit_cast(unsigned, f);
  u += 0x7FFFu + ((u >> 16) & 1u);
  return (unsigned short)(u >> 16);
}
__device__ __forceinline__ unsigned short bf2key(unsigned short b) {
  // monotone order-preserving key for bf16 bits
  return (b & 0x8000) ? (unsigned short)(~b) : (unsigned short)(b | 0x8000);
}

// ---------------------------------------------------------------------------
// K1: transpose W_router [DIM][NKN] -> WT fp32 [NKN][DIM] and WT bf16 [NKN][DIM]
// ---------------------------------------------------------------------------
__global__ __launch_bounds__(256) void k_transpose(const float* __restrict__ W,
                                                   float* __restrict__ WT,
                                                   unsigned short* __restrict__ WTb) {
  __shared__ float tile[32][33];
  const int n0 = (blockIdx.x & 2047) << 5;
  const int d0 = (blockIdx.x >> 11) << 5;
  const int c = threadIdx.x & 31, r0 = threadIdx.x >> 5;
#pragma unroll
  for (int i = 0; i < 4; i++) {
    int r = r0 + i * 8;
    tile[r][c] = W[(size_t)(d0 + r) * NKN + n0 + c];
  }
  __syncthreads();
#pragma unroll
  for (int i = 0; i < 4; i++) {
    int r = r0 + i * 8;
    float v = tile[c][r];  // = W[d0+c][n0+r]
    size_t o = (size_t)(n0 + r) * DIM + d0 + c;
    WT[o] = v;
    WTb[o] = f2bf(v);
  }
}

// ---------------------------------------------------------------------------
// K1b: convert x fp32 -> bf16
// ---------------------------------------------------------------------------
__global__ __launch_bounds__(256) void k_cvt_x(const float* __restrict__ x,
                                               unsigned short* __restrict__ xb) {
  const int i = blockIdx.x * 256 + threadIdx.x;
  const float4 v = reinterpret_cast<const float4*>(x)[i];
  ushort4 o;
  o.x = f2bf(v.x); o.y = f2bf(v.y); o.z = f2bf(v.z); o.w = f2bf(v.w);
  reinterpret_cast<ushort4*>(xb)[i] = o;
}

// ---------------------------------------------------------------------------
// K2: bf16 MFMA GEMM 128x128 tile, BK=64, XOR-swizzled LDS (T2 via rule-21:
// inverse-swizzled global source + linear global_load_lds dest + swizzled
// ds_read), XCD-chunked block swizzle, fused per-row chunk-max epilogue.
// ---------------------------------------------------------------------------
__global__ __launch_bounds__(256) void k_gemm(const unsigned short* __restrict__ A,
                                              const unsigned short* __restrict__ Bt,
                                              unsigned short* __restrict__ Lg,
                                              unsigned short* __restrict__ Cmax) {
  __shared__ __align__(16) unsigned short As[128 * 64];
  __shared__ __align__(16) unsigned short Bs[128 * 64];
  const int tid = threadIdx.x;
  const int lane = tid & 63, wid = tid >> 6;
  // bijective XCD-chunked swizzle (16384 % 8 == 0)
  const int wg = (blockIdx.x & 7) * 2048 + (blockIdx.x >> 3);
  const int mb = wg & 31, nb = wg >> 5;  // m-fast within each XCD's chunk
  const int m0 = mb << 7, n0 = nb << 7;
  const int wm = wid >> 1, wn = wid & 1;
  v4f acc[4][4] = {};

  // staging geometry: round p dest byte = p*4096 + tid*16
  // row = p*32 + (tid>>3); phys slot = tid&7; logical slot = (tid&7)^((tid>>3)&7)
  const int srow = tid >> 3;
  const int sl = (tid & 7) ^ (srow & 7);
  const unsigned short* aB = A + (size_t)(m0 + srow) * DIM + sl * 8;
  const unsigned short* bB = Bt + (size_t)(n0 + srow) * DIM + sl * 8;

  const int rm = lane & 15, lq = lane >> 4;

  for (int kt = 0; kt < DIM; kt += 64) {
    __syncthreads();
#pragma unroll
    for (int p = 0; p < 4; p++) {
      __builtin_amdgcn_global_load_lds((const AS1 void*)(aB + p * 32 * DIM + kt),
                                       (AS3 void*)(As + p * 2048 + wid * 512), 16, 0, 0);
      __builtin_amdgcn_global_load_lds((const AS1 void*)(bB + p * 32 * DIM + kt),
                                       (AS3 void*)(Bs + p * 2048 + wid * 512), 16, 0, 0);
    }
    __syncthreads();

    v8bf af[4][2], bfr[4][2];
    const char* Ac = (const char*)As;
    const char* Bc = (const char*)Bs;
#pragma unroll
    for (int i = 0; i < 4; i++) {
      const int rowa = wm * 64 + i * 16 + rm;
      const int rxa = (rowa & 7) << 4;
      const int rowb = wn * 64 + i * 16 + rm;
      const int rxb = (rowb & 7) << 4;
#pragma unroll
      for (int ks = 0; ks < 2; ks++) {
        af[i][ks] = *(const v8bf*)(Ac + rowa * 128 + ((ks * 64 + lq * 16) ^ rxa));
        bfr[i][ks] = *(const v8bf*)(Bc + rowb * 128 + ((ks * 64 + lq * 16) ^ rxb));
      }
    }
#pragma unroll
    for (int ks = 0; ks < 2; ks++)
#pragma unroll
      for (int i = 0; i < 4; i++)
#pragma unroll
        for (int j = 0; j < 4; j++)
          acc[i][j] = __builtin_amdgcn_mfma_f32_16x16x32_bf16(af[i][ks], bfr[j][ks], acc[i][j], 0, 0, 0);
  }

  // C/D layout: n = lane&15 (rm), m = lq*4 + reg
  const int mr = lq * 4;
  float rmax[4][4];
#pragma unroll
  for (int i = 0; i < 4; i++) {
#pragma unroll
    for (int r = 0; r < 4; r++) {
      float mx = acc[i][0][r];
#pragma unroll
      for (int j = 1; j < 4; j++) mx = fmaxf(mx, acc[i][j][r]);
      rmax[i][r] = mx;
    }
#pragma unroll
    for (int j = 0; j < 4; j++) {
      const int mrow = m0 + wm * 64 + i * 16 + mr;
      const int ncol = n0 + wn * 64 + j * 16 + rm;
#pragma unroll
      for (int r = 0; r < 4; r++)
        Lg[(size_t)(mrow + r) * NKN + ncol] = f2bf(acc[i][j][r]);
    }
  }
  // per-row max over this block's 128 cols: reduce across rm lanes, then waves
#pragma unroll
  for (int i = 0; i < 4; i++)
#pragma unroll
    for (int r = 0; r < 4; r++) {
#pragma unroll
      for (int off = 1; off < 16; off <<= 1)
        rmax[i][r] = fmaxf(rmax[i][r], __shfl_xor(rmax[i][r], off));
    }
  __syncthreads();               // As dead now; reuse as smax[2][128]
  float* smax = (float*)As;
  if (rm == 0) {
#pragma unroll
    for (int i = 0; i < 4; i++)
#pragma unroll
      for (int r = 0; r < 4; r++)
        smax[wn * 128 + wm * 64 + i * 16 + mr + r] = rmax[i][r];
  }
  __syncthreads();
  if (tid < 128) {
    float v = fmaxf(smax[tid], smax[128 + tid]);
    Cmax[(size_t)(m0 + tid) * NCHUNK + nb] = bf2key(f2bf(v));
  }
}

// ---------------------------------------------------------------------------
// K3: per-token candidate pick from chunk maxes.
// tau = 32nd-largest chunk-max key; collect all entries with key>>4 >= tau>>4
// (superset of the round-1 passing criterion). Reads only qualifying chunks.
// ---------------------------------------------------------------------------
__global__ __launch_bounds__(256) void k_pick(const unsigned short* __restrict__ Cmax,
                                              const unsigned short* __restrict__ Lg,
                                              int* __restrict__ cidx,
                                              int* __restrict__ ccnt) {
  __shared__ unsigned short keys[NCHUNK];
  __shared__ int qlist[NCHUNK];
  __shared__ int qn, scnt, bsS;
  const int t = blockIdx.x, tid = threadIdx.x;
  const int lane = tid & 63, w = tid >> 6;
  keys[tid] = Cmax[(size_t)t * NCHUNK + tid];
  keys[tid + 256] = Cmax[(size_t)t * NCHUNK + tid + 256];
  if (tid == 0) { qn = 0; scnt = 0; }
  __syncthreads();
  if (w == 0) {
    int v[8];
#pragma unroll
    for (int j = 0; j < 8; j++) v[j] = keys[lane * 8 + j];
    int t32 = 0;
    for (int it = 0; it < 32; it++) {
      int lm = v[0];
#pragma unroll
      for (int j = 1; j < 8; j++) lm = max(lm, v[j]);
      int gm = lm;
#pragma unroll
      for (int off = 32; off > 0; off >>= 1) gm = max(gm, __shfl_xor(gm, off));
      unsigned long long msk = __ballot(lm == gm);
      if (lane == __ffsll((long long)msk) - 1) {
        bool done = false;
#pragma unroll
        for (int j = 0; j < 8; j++)
          if (!done && v[j] == gm) { v[j] = -1; done = true; }
      }
      t32 = gm;
    }
    if (lane == 0) bsS = t32 >> 4;
  }
  __syncthreads();
  const int bs = bsS;
  for (int c = tid; c < NCHUNK; c += 256)
    if ((keys[c] >> 4) >= bs) { int p = atomicAdd(&qn, 1); qlist[p] = c; }
  __syncthreads();
  const int nq = qn;
  const int sub = tid >> 7, e = tid & 127;
  for (int qi = sub; qi < nq; qi += 2) {
    const int col = qlist[qi] * 128 + e;
    unsigned short key = bf2key(Lg[(size_t)t * NKN + col]);
    if ((int)(key >> 4) >= bs) {
      int p = atomicAdd(&scnt, 1);
      if (p < CAP) cidx[(size_t)t * CAP + p] = col;
    }
  }
  __syncthreads();
  if (tid == 0) ccnt[t] = min(scnt, CAP);
}

// ---------------------------------------------------------------------------
// K4: exact fp64 rescore of candidates + exact top-20 selection
// ---------------------------------------------------------------------------
__global__ __launch_bounds__(256) void k_rescore(const float* __restrict__ x,
                                                 const float* __restrict__ WT,
                                                 const int* __restrict__ cidx,
                                                 const int* __restrict__ ccnt,
                                                 int* __restrict__ coarse) {
  __shared__ float xs[DIM];
  __shared__ double sc[CAP];
  __shared__ int ci[CAP];
  const int t = blockIdx.x, tid = threadIdx.x;
  const int lane = tid & 63, w = tid >> 6;
  const int cnt = ccnt[t];
  for (int i = tid; i < DIM; i += 256) xs[i] = x[(size_t)t * DIM + i];
  for (int i = tid; i < CAP; i += 256) {
    sc[i] = -1e300;
    ci[i] = (i < cnt) ? cidx[(size_t)t * CAP + i] : 0;
  }
  __syncthreads();
  for (int c = w; c < cnt; c += 4) {
    const float* wr = WT + (size_t)ci[c] * DIM;
    double sacc = 0.0;
#pragma unroll 4
    for (int i = lane; i < DIM; i += 64) sacc += (double)xs[i] * (double)wr[i];
#pragma unroll
    for (int off = 32; off > 0; off >>= 1) sacc += __shfl_down(sacc, off);
    if (lane == 0) sc[c] = sacc;
  }
  __syncthreads();
  if (w == 0) {
    double v[4];
    int ix[4];
#pragma unroll
    for (int j = 0; j < 4; j++) { v[j] = sc[lane + j * 64]; ix[j] = lane + j * 64; }
    for (int kk = 0; kk < CK; kk++) {
      double v1 = v[0]; int i1 = ix[0];
#pragma unroll
      for (int j = 1; j < 4; j++)
        if (v[j] > v1) { v1 = v[j]; i1 = ix[j]; }
#pragma unroll
      for (int off = 32; off > 0; off >>= 1) {
        double ov = __shfl_down(v1, off);
        int oi = __shfl_down(i1, off);
        if (ov > v1) { v1 = ov; i1 = oi; }
      }
      i1 = __shfl(i1, 0);
      if (lane == 0) coarse[(size_t)t * CK + kk] = ci[i1];
#pragma unroll
      for (int j = 0; j < 4; j++)
        if (i1 == ix[j]) v[j] = -1e300;
    }
  }
}

// ---------------------------------------------------------------------------
// K5: query = x @ W_enc
// ---------------------------------------------------------------------------
__global__ __launch_bounds__(128) void k_query(const float* __restrict__ x,
                                               const float* __restrict__ Wenc,
                                               float* __restrict__ q) {
  const int j = threadIdx.x;
  const int t0 = blockIdx.x * 4;
  float s0 = 0.f, s1 = 0.f, s2 = 0.f, s3 = 0.f;
  const float* x0 = x + (size_t)t0 * DIM;
  for (int d = 0; d < DIM; d++) {
    float wv = Wenc[d * RNK + j];
    s0 = fmaf(x0[d], wv, s0);
    s1 = fmaf(x0[DIM + d], wv, s1);
    s2 = fmaf(x0[2 * DIM + d], wv, s2);
    s3 = fmaf(x0[3 * DIM + d], wv, s3);
  }
  q[(size_t)t0 * RNK + j] = s0;
  q[(size_t)(t0 + 1) * RNK + j] = s1;
  q[(size_t)(t0 + 2) * RNK + j] = s2;
  q[(size_t)(t0 + 3) * RNK + j] = s3;
}

// ---------------------------------------------------------------------------
// K6: fine scores vs 20 candidates, top-10, softmax, weighted V blend
// ---------------------------------------------------------------------------
__global__ __launch_bounds__(256) void k_fine(const float* __restrict__ q,
                                              const float* __restrict__ Kall,
                                              const float* __restrict__ Vall,
                                              const int* __restrict__ coarse,
                                              float* __restrict__ out) {
  __shared__ float qs[RNK];
  __shared__ float fsc[CK];
  __shared__ int gix[CK];
  __shared__ float wts[FK];
  __shared__ int fidx[FK];
  const int t = blockIdx.x, tid = threadIdx.x;
  const int lane = tid & 63, w = tid >> 6;
  if (tid < RNK) qs[tid] = q[(size_t)t * RNK + tid];
  if (tid < CK) gix[tid] = coarse[(size_t)t * CK + tid];
  __syncthreads();
  for (int c = w; c < CK; c += 4) {
    const float* kr = Kall + (size_t)gix[c] * RNK;
    float s = 0.f;
    s = fmaf(qs[lane], kr[lane], s);
    s = fmaf(qs[lane + 64], kr[lane + 64], s);
#pragma unroll
    for (int off = 32; off > 0; off >>= 1) s += __shfl_down(s, off);
    if (lane == 0) fsc[c] = s * 0.08838834764831843f;  // 1/sqrt(128)
  }
  __syncthreads();
  if (w == 0) {
    float vv = (lane < CK) ? fsc[lane] : -3e38f;
    float myv = -3e38f; int myp = 0;
    for (int kk = 0; kk < FK; kk++) {
      float v1 = vv; int p1 = lane;
#pragma unroll
      for (int off = 32; off > 0; off >>= 1) {
        float ov = __shfl_down(v1, off);
        int op = __shfl_down(p1, off);
        if (ov > v1) { v1 = ov; p1 = op; }
      }
      v1 = __shfl(v1, 0); p1 = __shfl(p1, 0);
      if (lane == kk) { myv = v1; myp = p1; }
      if (lane == p1) vv = -3e38f;
    }
    float sv = (lane < FK) ? myv : -3e38f;
    float mx = sv;
#pragma unroll
    for (int off = 8; off > 0; off >>= 1) mx = fmaxf(mx, __shfl_xor(mx, off, 16));
    float e = (lane < FK) ? expf(sv - mx) : 0.f;
    float se = e;
#pragma unroll
    for (int off = 8; off > 0; off >>= 1) se += __shfl_xor(se, off, 16);
    if (lane < FK) { wts[lane] = e / se; fidx[lane] = gix[myp]; }
  }
  __syncthreads();
  float4 a = make_float4(0.f, 0.f, 0.f, 0.f);
#pragma unroll
  for (int f = 0; f < FK; f++) {
    const float wt = wts[f];
    const float4 v = *reinterpret_cast<const float4*>(&Vall[(size_t)fidx[f] * DIM + tid * 4]);
    a.x = fmaf(wt, v.x, a.x);
    a.y = fmaf(wt, v.y, a.y);
    a.z = fmaf(wt, v.z, a.z);
    a.w = fmaf(wt, v.w, a.w);
  }
  *reinterpret_cast<float4*>(&out[(size_t)t * DIM + tid * 4]) = a;
}

// ---------------------------------------------------------------------------

extern "C" void kernel_launch(void* const* d_in, const int* in_sizes, int n_in,
                              void* d_out, int out_size, void* d_ws, size_t ws_size,
                              hipStream_t stream) {
  const float* x = (const float*)d_in[0];      // [4096][1024]
  const float* Wr = (const float*)d_in[1];     // [1024][65536]
  const float* Wenc = (const float*)d_in[2];   // [1024][128]
  const float* Kall = (const float*)d_in[3];   // [65536][128]
  const float* Vall = (const float*)d_in[4];   // [65536][1024]
  float* out = (float*)d_out;                  // [4096][1024]

  char* ws = (char*)d_ws;
  constexpr size_t OFF_WT = 0;                  // fp32 W^T    256 MB (live until rescore)
  constexpr size_t OFF_WTB = 268435456;         // bf16 W^T    128 MB (dead after gemm)
  constexpr size_t OFF_XB = 402653184;          // bf16 x        8 MB (dead after gemm)
  constexpr size_t OFF_LG = 411041792;          // bf16 logits 512 MB
  constexpr size_t OFF_CMAX = 947912704;        // chunk-max keys 4 MB (ends 952107008)
  float* WT = (float*)(ws + OFF_WT);
  unsigned short* WTb = (unsigned short*)(ws + OFF_WTB);
  unsigned short* xb = (unsigned short*)(ws + OFF_XB);
  unsigned short* Lg = (unsigned short*)(ws + OFF_LG);
  unsigned short* Cmax = (unsigned short*)(ws + OFF_CMAX);
  // aliases into regions that are dead after k_gemm:
  int* cidx = (int*)(ws + OFF_XB);                        // 4 MB
  int* ccnt = (int*)(ws + OFF_XB + 4194304);              // 16 KB
  int* coarse = (int*)(ws + OFF_XB + 4259840);            // 320 KB
  float* q = (float*)(ws + OFF_WTB);                      // 2 MB

  k_transpose<<<65536, 256, 0, stream>>>(Wr, WT, WTb);
  k_cvt_x<<<4096, 256, 0, stream>>>(x, xb);
  k_gemm<<<16384, 256, 0, stream>>>(xb, WTb, Lg, Cmax);
  k_pick<<<4096, 256, 0, stream>>>(Cmax, Lg, cidx, ccnt);
  k_rescore<<<4096, 256, 0, stream>>>(x, WT, cidx, ccnt, coarse);
  k_query<<<1024, 128, 0, stream>>>(x, Wenc, q);
  k_fine<<<4096, 256, 0, stream>>>(q, Kall, Vall, coarse, out);
}

// Round 3
// 1531.576 us; speedup vs baseline: 1.2025x; 1.2025x over previous
//
#include <hip/hip_runtime.h>

#define DIM 1024
#define NKN 65536
#define TOK 4096
#define CK 20
#define FK 10
#define RNK 128
#define CAP 256
#define NCHUNK 512   // 65536 / 128 cols per GEMM block

typedef __bf16 v8bf __attribute__((ext_vector_type(8)));
typedef float v4f __attribute__((ext_vector_type(4)));

#define AS1 __attribute__((address_space(1)))
#define AS3 __attribute__((address_space(3)))

__device__ __forceinline__ unsigned short f2bf(float f) {
  // round-to-nearest-even fp32 -> bf16 (finite inputs only)
  unsigned u = __builtin_bit_cast(unsigned, f);
  u += 0x7FFFu + ((u >> 16) & 1u);
  return (unsigned short)(u >> 16);
}
__device__ __forceinline__ unsigned short bf2key(unsigned short b) {
  // monotone order-preserving key for bf16 bits
  return (b & 0x8000) ? (unsigned short)(~b) : (unsigned short)(b | 0x8000);
}

// ---------------------------------------------------------------------------
// K1: transpose W_router [DIM][NKN] -> WT fp32 [NKN][DIM] and WT bf16 [NKN][DIM]
// ---------------------------------------------------------------------------
__global__ __launch_bounds__(256) void k_transpose(const float* __restrict__ W,
                                                   float* __restrict__ WT,
                                                   unsigned short* __restrict__ WTb) {
  __shared__ float tile[32][33];
  const int n0 = (blockIdx.x & 2047) << 5;
  const int d0 = (blockIdx.x >> 11) << 5;
  const int c = threadIdx.x & 31, r0 = threadIdx.x >> 5;
#pragma unroll
  for (int i = 0; i < 4; i++) {
    int r = r0 + i * 8;
    tile[r][c] = W[(size_t)(d0 + r) * NKN + n0 + c];
  }
  __syncthreads();
#pragma unroll
  for (int i = 0; i < 4; i++) {
    int r = r0 + i * 8;
    float v = tile[c][r];  // = W[d0+c][n0+r]
    size_t o = (size_t)(n0 + r) * DIM + d0 + c;
    WT[o] = v;
    WTb[o] = f2bf(v);
  }
}

// ---------------------------------------------------------------------------
// K1b: convert x fp32 -> bf16
// ---------------------------------------------------------------------------
__global__ __launch_bounds__(256) void k_cvt_x(const float* __restrict__ x,
                                               unsigned short* __restrict__ xb) {
  const int i = blockIdx.x * 256 + threadIdx.x;
  const float4 v = reinterpret_cast<const float4*>(x)[i];
  ushort4 o;
  o.x = f2bf(v.x); o.y = f2bf(v.y); o.z = f2bf(v.z); o.w = f2bf(v.w);
  reinterpret_cast<ushort4*>(xb)[i] = o;
}

// ---------------------------------------------------------------------------
// K2: bf16 MFMA GEMM, round-1 structure (128x128 tile, BK=32, 16 KB LDS,
// 4 waves 2x2, 16x16x32 MFMA, global_load_lds width=16).
// LDS tiles re-laid out as [64 phys rows][128 B] with slot-XOR so ds_read_b128
// is 2-way (free) instead of 8-way: phys(row,ks) = (row&63)*128B +
// (((row>>6)*4+ks)^(row&7))*16B. Applied rule-21-correctly: linear LDS dest,
// inverse-permuted GLOBAL source, same permutation on ds_read.
// Fused epilogue: per-row max over this block's 128 cols -> CmaxT[nb][row]
// (contiguous 256 B store per block).
// ---------------------------------------------------------------------------
__global__ __launch_bounds__(256) void k_gemm(const unsigned short* __restrict__ A,
                                              const unsigned short* __restrict__ Bt,
                                              unsigned short* __restrict__ Lg,
                                              unsigned short* __restrict__ CmaxT) {
  __shared__ __align__(16) unsigned short As[64 * 64];  // 8 KB
  __shared__ __align__(16) unsigned short Bs[64 * 64];  // 8 KB
  const int tid = threadIdx.x;
  const int lane = tid & 63, wid = tid >> 6;
  const int mb = blockIdx.x & 31, nb = blockIdx.x >> 5;  // m-fast: B tile reused
  const int m0 = mb << 7, n0 = nb << 7;
  const int wm = wid >> 1, wn = wid & 1;
  v4f acc[4][4] = {};

  // staging: phys byte for round q = q*4096 + tid*16
  //   phys row R = q*32 + (tid>>3), phys slot S = tid&7
  //   u = S ^ (R&7) = S ^ ((tid>>3)&7)   (32 = 0 mod 8, q-independent)
  //   logical row = (u>>2)*64 + R, k-offset = (u&3)*8
  const int Rq = tid >> 3, S = tid & 7;
  const int u = S ^ (Rq & 7);
  const int lr0 = (u >> 2) * 64 + Rq;   // q=0 rows (R in 0..31)
  const int lr1 = lr0 + 32;             // q=1 rows (R in 32..63)
  const int kof = (u & 3) * 8;
  const unsigned short* a0 = A + (size_t)(m0 + lr0) * DIM + kof;
  const unsigned short* a1 = A + (size_t)(m0 + lr1) * DIM + kof;
  const unsigned short* b0 = Bt + (size_t)(n0 + lr0) * DIM + kof;
  const unsigned short* b1 = Bt + (size_t)(n0 + lr1) * DIM + kof;
  unsigned short* lA0 = &As[wid * 512];          // wave-uniform LDS bases
  unsigned short* lA1 = &As[2048 + wid * 512];
  unsigned short* lB0 = &Bs[wid * 512];
  unsigned short* lB1 = &Bs[2048 + wid * 512];

  const int rm = lane & 15, lq = lane >> 4;
  // ds_read byte offsets: (i*16+rm)*128 + ((w*4+lq)^(rm&7))*16
  const int sa = (((wm * 4 + lq) ^ (rm & 7)) << 4);
  const int sb = (((wn * 4 + lq) ^ (rm & 7)) << 4);
  const char* Ac = (const char*)As;
  const char* Bc = (const char*)Bs;

  for (int kt = 0; kt < DIM; kt += 32) {
    __syncthreads();
    __builtin_amdgcn_global_load_lds((const AS1 void*)(a0 + kt), (AS3 void*)lA0, 16, 0, 0);
    __builtin_amdgcn_global_load_lds((const AS1 void*)(a1 + kt), (AS3 void*)lA1, 16, 0, 0);
    __builtin_amdgcn_global_load_lds((const AS1 void*)(b0 + kt), (AS3 void*)lB0, 16, 0, 0);
    __builtin_amdgcn_global_load_lds((const AS1 void*)(b1 + kt), (AS3 void*)lB1, 16, 0, 0);
    __syncthreads();

    v8bf af[4], bfr[4];
#pragma unroll
    for (int i = 0; i < 4; i++)
      af[i] = *(const v8bf*)(Ac + (i * 16 + rm) * 128 + sa);
#pragma unroll
    for (int i = 0; i < 4; i++)
      bfr[i] = *(const v8bf*)(Bc + (i * 16 + rm) * 128 + sb);
#pragma unroll
    for (int i = 0; i < 4; i++)
#pragma unroll
      for (int j = 0; j < 4; j++)
        acc[i][j] = __builtin_amdgcn_mfma_f32_16x16x32_bf16(af[i], bfr[j], acc[i][j], 0, 0, 0);
  }

  // C/D layout (verified m89/m91): n = lane&15 (rm), m = lq*4 + reg
  const int mr = lq * 4;
  float rmax[4][4];
#pragma unroll
  for (int i = 0; i < 4; i++) {
#pragma unroll
    for (int r = 0; r < 4; r++) {
      float mx = acc[i][0][r];
#pragma unroll
      for (int j = 1; j < 4; j++) mx = fmaxf(mx, acc[i][j][r]);
      rmax[i][r] = mx;
    }
#pragma unroll
    for (int j = 0; j < 4; j++) {
      const int mrow = m0 + wm * 64 + i * 16 + mr;
      const int ncol = n0 + wn * 64 + j * 16 + rm;
#pragma unroll
      for (int r = 0; r < 4; r++)
        Lg[(size_t)(mrow + r) * NKN + ncol] = f2bf(acc[i][j][r]);
    }
  }
  // per-row max across this block's 128 cols: reduce over rm lanes, then waves
#pragma unroll
  for (int i = 0; i < 4; i++)
#pragma unroll
    for (int r = 0; r < 4; r++) {
#pragma unroll
      for (int off = 1; off < 16; off <<= 1)
        rmax[i][r] = fmaxf(rmax[i][r], __shfl_xor(rmax[i][r], off));
    }
  __syncthreads();               // As dead now; reuse as smax[2][128]
  float* smax = (float*)As;
  if (rm == 0) {
#pragma unroll
    for (int i = 0; i < 4; i++)
#pragma unroll
      for (int r = 0; r < 4; r++)
        smax[wn * 128 + wm * 64 + i * 16 + mr + r] = rmax[i][r];
  }
  __syncthreads();
  if (tid < 128) {
    float v = fmaxf(smax[tid], smax[128 + tid]);
    CmaxT[(size_t)nb * TOK + m0 + tid] = bf2key(f2bf(v));  // contiguous 256 B
  }
}

// ---------------------------------------------------------------------------
// K3: per-token candidate pick from chunk maxes (CmaxT layout [NCHUNK][TOK]).
// tau = 32nd-largest chunk-max key; collect all entries with key>>4 >= tau>>4
// (superset of the round-1 passing criterion). Reads only qualifying chunks.
// ---------------------------------------------------------------------------
__global__ __launch_bounds__(256) void k_pick(const unsigned short* __restrict__ CmaxT,
                                              const unsigned short* __restrict__ Lg,
                                              int* __restrict__ cidx,
                                              int* __restrict__ ccnt) {
  __shared__ unsigned short keys[NCHUNK];
  __shared__ int qlist[NCHUNK];
  __shared__ int qn, scnt, bsS;
  const int t = blockIdx.x, tid = threadIdx.x;
  const int lane = tid & 63, w = tid >> 6;
  keys[tid] = CmaxT[(size_t)tid * TOK + t];
  keys[tid + 256] = CmaxT[(size_t)(tid + 256) * TOK + t];
  if (tid == 0) { qn = 0; scnt = 0; }
  __syncthreads();
  if (w == 0) {
    int v[8];
#pragma unroll
    for (int j = 0; j < 8; j++) v[j] = keys[lane * 8 + j];
    int t32 = 0;
    for (int it = 0; it < 32; it++) {
      int lm = v[0];
#pragma unroll
      for (int j = 1; j < 8; j++) lm = max(lm, v[j]);
      int gm = lm;
#pragma unroll
      for (int off = 32; off > 0; off >>= 1) gm = max(gm, __shfl_xor(gm, off));
      unsigned long long msk = __ballot(lm == gm);
      if (lane == __ffsll((long long)msk) - 1) {
        bool done = false;
#pragma unroll
        for (int j = 0; j < 8; j++)
          if (!done && v[j] == gm) { v[j] = -1; done = true; }
      }
      t32 = gm;
    }
    if (lane == 0) bsS = t32 >> 4;
  }
  __syncthreads();
  const int bs = bsS;
  for (int c = tid; c < NCHUNK; c += 256)
    if ((keys[c] >> 4) >= bs) { int p = atomicAdd(&qn, 1); qlist[p] = c; }
  __syncthreads();
  const int nq = qn;
  const int sub = tid >> 7, e = tid & 127;
  for (int qi = sub; qi < nq; qi += 2) {
    const int col = qlist[qi] * 128 + e;
    unsigned short key = bf2key(Lg[(size_t)t * NKN + col]);
    if ((int)(key >> 4) >= bs) {
      int p = atomicAdd(&scnt, 1);
      if (p < CAP) cidx[(size_t)t * CAP + p] = col;
    }
  }
  __syncthreads();
  if (tid == 0) ccnt[t] = min(scnt, CAP);
}

// ---------------------------------------------------------------------------
// K4: exact fp64 rescore of candidates + exact top-20 selection
// ---------------------------------------------------------------------------
__global__ __launch_bounds__(256) void k_rescore(const float* __restrict__ x,
                                                 const float* __restrict__ WT,
                                                 const int* __restrict__ cidx,
                                                 const int* __restrict__ ccnt,
                                                 int* __restrict__ coarse) {
  __shared__ float xs[DIM];
  __shared__ double sc[CAP];
  __shared__ int ci[CAP];
  const int t = blockIdx.x, tid = threadIdx.x;
  const int lane = tid & 63, w = tid >> 6;
  const int cnt = ccnt[t];
  for (int i = tid; i < DIM; i += 256) xs[i] = x[(size_t)t * DIM + i];
  for (int i = tid; i < CAP; i += 256) {
    sc[i] = -1e300;
    ci[i] = (i < cnt) ? cidx[(size_t)t * CAP + i] : 0;
  }
  __syncthreads();
  for (int c = w; c < cnt; c += 4) {
    const float* wr = WT + (size_t)ci[c] * DIM;
    double sacc = 0.0;
#pragma unroll 4
    for (int i = lane; i < DIM; i += 64) sacc += (double)xs[i] * (double)wr[i];
#pragma unroll
    for (int off = 32; off > 0; off >>= 1) sacc += __shfl_down(sacc, off);
    if (lane == 0) sc[c] = sacc;
  }
  __syncthreads();
  if (w == 0) {
    double v[4];
    int ix[4];
#pragma unroll
    for (int j = 0; j < 4; j++) { v[j] = sc[lane + j * 64]; ix[j] = lane + j * 64; }
    for (int kk = 0; kk < CK; kk++) {
      double v1 = v[0]; int i1 = ix[0];
#pragma unroll
      for (int j = 1; j < 4; j++)
        if (v[j] > v1) { v1 = v[j]; i1 = ix[j]; }
#pragma unroll
      for (int off = 32; off > 0; off >>= 1) {
        double ov = __shfl_down(v1, off);
        int oi = __shfl_down(i1, off);
        if (ov > v1) { v1 = ov; i1 = oi; }
      }
      i1 = __shfl(i1, 0);
      if (lane == 0) coarse[(size_t)t * CK + kk] = ci[i1];
#pragma unroll
      for (int j = 0; j < 4; j++)
        if (i1 == ix[j]) v[j] = -1e300;
    }
  }
}

// ---------------------------------------------------------------------------
// K5: query = x @ W_enc
// ---------------------------------------------------------------------------
__global__ __launch_bounds__(128) void k_query(const float* __restrict__ x,
                                               const float* __restrict__ Wenc,
                                               float* __restrict__ q) {
  const int j = threadIdx.x;
  const int t0 = blockIdx.x * 4;
  float s0 = 0.f, s1 = 0.f, s2 = 0.f, s3 = 0.f;
  const float* x0 = x + (size_t)t0 * DIM;
  for (int d = 0; d < DIM; d++) {
    float wv = Wenc[d * RNK + j];
    s0 = fmaf(x0[d], wv, s0);
    s1 = fmaf(x0[DIM + d], wv, s1);
    s2 = fmaf(x0[2 * DIM + d], wv, s2);
    s3 = fmaf(x0[3 * DIM + d], wv, s3);
  }
  q[(size_t)t0 * RNK + j] = s0;
  q[(size_t)(t0 + 1) * RNK + j] = s1;
  q[(size_t)(t0 + 2) * RNK + j] = s2;
  q[(size_t)(t0 + 3) * RNK + j] = s3;
}

// ---------------------------------------------------------------------------
// K6: fine scores vs 20 candidates, top-10, softmax, weighted V blend
// ---------------------------------------------------------------------------
__global__ __launch_bounds__(256) void k_fine(const float* __restrict__ q,
                                              const float* __restrict__ Kall,
                                              const float* __restrict__ Vall,
                                              const int* __restrict__ coarse,
                                              float* __restrict__ out) {
  __shared__ float qs[RNK];
  __shared__ float fsc[CK];
  __shared__ int gix[CK];
  __shared__ float wts[FK];
  __shared__ int fidx[FK];
  const int t = blockIdx.x, tid = threadIdx.x;
  const int lane = tid & 63, w = tid >> 6;
  if (tid < RNK) qs[tid] = q[(size_t)t * RNK + tid];
  if (tid < CK) gix[tid] = coarse[(size_t)t * CK + tid];
  __syncthreads();
  for (int c = w; c < CK; c += 4) {
    const float* kr = Kall + (size_t)gix[c] * RNK;
    float s = 0.f;
    s = fmaf(qs[lane], kr[lane], s);
    s = fmaf(qs[lane + 64], kr[lane + 64], s);
#pragma unroll
    for (int off = 32; off > 0; off >>= 1) s += __shfl_down(s, off);
    if (lane == 0) fsc[c] = s * 0.08838834764831843f;  // 1/sqrt(128)
  }
  __syncthreads();
  if (w == 0) {
    float vv = (lane < CK) ? fsc[lane] : -3e38f;
    float myv = -3e38f; int myp = 0;
    for (int kk = 0; kk < FK; kk++) {
      float v1 = vv; int p1 = lane;
#pragma unroll
      for (int off = 32; off > 0; off >>= 1) {
        float ov = __shfl_down(v1, off);
        int op = __shfl_down(p1, off);
        if (ov > v1) { v1 = ov; p1 = op; }
      }
      v1 = __shfl(v1, 0); p1 = __shfl(p1, 0);
      if (lane == kk) { myv = v1; myp = p1; }
      if (lane == p1) vv = -3e38f;
    }
    float sv = (lane < FK) ? myv : -3e38f;
    float mx = sv;
#pragma unroll
    for (int off = 8; off > 0; off >>= 1) mx = fmaxf(mx, __shfl_xor(mx, off, 16));
    float e = (lane < FK) ? expf(sv - mx) : 0.f;
    float se = e;
#pragma unroll
    for (int off = 8; off > 0; off >>= 1) se += __shfl_xor(se, off, 16);
    if (lane < FK) { wts[lane] = e / se; fidx[lane] = gix[myp]; }
  }
  __syncthreads();
  float4 a = make_float4(0.f, 0.f, 0.f, 0.f);
#pragma unroll
  for (int f = 0; f < FK; f++) {
    const float wt = wts[f];
    const float4 v = *reinterpret_cast<const float4*>(&Vall[(size_t)fidx[f] * DIM + tid * 4]);
    a.x = fmaf(wt, v.x, a.x);
    a.y = fmaf(wt, v.y, a.y);
    a.z = fmaf(wt, v.z, a.z);
    a.w = fmaf(wt, v.w, a.w);
  }
  *reinterpret_cast<float4*>(&out[(size_t)t * DIM + tid * 4]) = a;
}

// ---------------------------------------------------------------------------

extern "C" void kernel_launch(void* const* d_in, const int* in_sizes, int n_in,
                              void* d_out, int out_size, void* d_ws, size_t ws_size,
                              hipStream_t stream) {
  const float* x = (const float*)d_in[0];      // [4096][1024]
  const float* Wr = (const float*)d_in[1];     // [1024][65536]
  const float* Wenc = (const float*)d_in[2];   // [1024][128]
  const float* Kall = (const float*)d_in[3];   // [65536][128]
  const float* Vall = (const float*)d_in[4];   // [65536][1024]
  float* out = (float*)d_out;                  // [4096][1024]

  char* ws = (char*)d_ws;
  constexpr size_t OFF_WT = 0;                  // fp32 W^T    256 MB (live until rescore)
  constexpr size_t OFF_WTB = 268435456;         // bf16 W^T    128 MB (dead after gemm)
  constexpr size_t OFF_XB = 402653184;          // bf16 x        8 MB (dead after gemm)
  constexpr size_t OFF_LG = 411041792;          // bf16 logits 512 MB
  constexpr size_t OFF_CMAX = 947912704;        // chunk-max keys 4 MB (ends 952107008)
  float* WT = (float*)(ws + OFF_WT);
  unsigned short* WTb = (unsigned short*)(ws + OFF_WTB);
  unsigned short* xb = (unsigned short*)(ws + OFF_XB);
  unsigned short* Lg = (unsigned short*)(ws + OFF_LG);
  unsigned short* CmaxT = (unsigned short*)(ws + OFF_CMAX);
  // aliases into regions that are dead after k_gemm:
  int* cidx = (int*)(ws + OFF_XB);                        // 4 MB
  int* ccnt = (int*)(ws + OFF_XB + 4194304);              // 16 KB
  int* coarse = (int*)(ws + OFF_XB + 4259840);            // 320 KB
  float* q = (float*)(ws + OFF_WTB);                      // 2 MB

  k_transpose<<<65536, 256, 0, stream>>>(Wr, WT, WTb);
  k_cvt_x<<<4096, 256, 0, stream>>>(x, xb);
  k_gemm<<<16384, 256, 0, stream>>>(xb, WTb, Lg, CmaxT);
  k_pick<<<4096, 256, 0, stream>>>(CmaxT, Lg, cidx, ccnt);
  k_rescore<<<4096, 256, 0, stream>>>(x, WT, cidx, ccnt, coarse);
  k_query<<<1024, 128, 0, stream>>>(x, Wenc, q);
  k_fine<<<4096, 256, 0, stream>>>(q, Kall, Vall, coarse, out);
}

// Round 4
// 1225.898 us; speedup vs baseline: 1.5023x; 1.2494x over previous
//
#include <hip/hip_runtime.h>

#define DIM 1024
#define NKN 65536
#define TOK 4096
#define CK 20
#define FK 10
#define RNK 128
#define CAP 256
#define NCHUNK 256   // 65536 / 256 cols per GEMM block

typedef __bf16 v8bf __attribute__((ext_vector_type(8)));
typedef float v4f __attribute__((ext_vector_type(4)));

#define AS1 __attribute__((address_space(1)))
#define AS3 __attribute__((address_space(3)))

__device__ __forceinline__ unsigned short f2bf(float f) {
  // round-to-nearest-even fp32 -> bf16 (finite inputs only)
  unsigned u = __builtin_bit_cast(unsigned, f);
  u += 0x7FFFu + ((u >> 16) & 1u);
  return (unsigned short)(u >> 16);
}
__device__ __forceinline__ unsigned short bf2key(unsigned short b) {
  // monotone order-preserving key for bf16 bits
  return (b & 0x8000) ? (unsigned short)(~b) : (unsigned short)(b | 0x8000);
}

// ---------------------------------------------------------------------------
// K1: transpose W_router [DIM][NKN] -> WT fp32 [NKN][DIM] and WT bf16 [NKN][DIM]
// ---------------------------------------------------------------------------
__global__ __launch_bounds__(256) void k_transpose(const float* __restrict__ W,
                                                   float* __restrict__ WT,
                                                   unsigned short* __restrict__ WTb) {
  __shared__ float tile[32][33];
  const int n0 = (blockIdx.x & 2047) << 5;
  const int d0 = (blockIdx.x >> 11) << 5;
  const int c = threadIdx.x & 31, r0 = threadIdx.x >> 5;
#pragma unroll
  for (int i = 0; i < 4; i++) {
    int r = r0 + i * 8;
    tile[r][c] = W[(size_t)(d0 + r) * NKN + n0 + c];
  }
  __syncthreads();
#pragma unroll
  for (int i = 0; i < 4; i++) {
    int r = r0 + i * 8;
    float v = tile[c][r];  // = W[d0+c][n0+r]
    size_t o = (size_t)(n0 + r) * DIM + d0 + c;
    WT[o] = v;
    WTb[o] = f2bf(v);
  }
}

// ---------------------------------------------------------------------------
// K1b: convert x fp32 -> bf16
// ---------------------------------------------------------------------------
__global__ __launch_bounds__(256) void k_cvt_x(const float* __restrict__ x,
                                               unsigned short* __restrict__ xb) {
  const int i = blockIdx.x * 256 + threadIdx.x;
  const float4 v = reinterpret_cast<const float4*>(x)[i];
  ushort4 o;
  o.x = f2bf(v.x); o.y = f2bf(v.y); o.z = f2bf(v.z); o.w = f2bf(v.w);
  reinterpret_cast<ushort4*>(xb)[i] = o;
}

// ---------------------------------------------------------------------------
// K2: deep-pipelined bf16 MFMA GEMM (T3+T4).
// 256x256 tile, BK=32, 512 threads = 8 waves (2M x 4N), per-wave C = 128x64.
// LDS = 4-slot ring (4 x 32 KiB = 128 KiB), prefetch distance 3 K-tiles,
// counted vmcnt(12) fused with raw s_barrier (loads stay in flight across
// barriers; never drains to 0 in the main loop).
// Ring safety: iteration t stages tile t+3 into slot (t+3)&3 = slot of tile
// t-1, whose LDS reads all completed before the end-of-(t-1) barrier.
// LDS layout: 64-B rows, 4 x 16-B slots, phys slot = logical ^ ((row>>1)&3)
// -> per-16-lane-group ds_read_b128 hits each bank exactly twice (free).
// Applied rule-21: linear global_load_lds dest + inverse-permuted global src
// + same permutation on ds_read address.
// Fused epilogue: per-row max over the block's 256 cols -> CmaxT[nb][row].
// ---------------------------------------------------------------------------
__global__ __launch_bounds__(512, 2) void k_gemm(const unsigned short* __restrict__ A,
                                                 const unsigned short* __restrict__ Bt,
                                                 unsigned short* __restrict__ Lg,
                                                 unsigned short* __restrict__ CmaxT) {
  __shared__ __align__(16) char lds[131072];  // ring[4]: {A 16 KB, B 16 KB}
  const int tid = threadIdx.x;
  const int lane = tid & 63, wid = tid >> 6;
  const int wm = wid >> 2, wn = wid & 3;
  const int mb = blockIdx.x & 15, nb = blockIdx.x >> 4;  // m-fast: B-panel reuse
  const int m0 = mb << 8, n0 = nb << 8;
  const int rm = lane & 15, lq = lane >> 4;
  v4f acc[8][4] = {};

  // staging source (inverse-permuted): thread covers phys row tid>>2, slot tid&3
  // logical k-slot u = (tid&3) ^ ((tid>>3)&3)
  const int u8 = (((tid & 3) ^ ((tid >> 3) & 3)) << 3);
  const unsigned short* aSrc = A + (size_t)(m0 + (tid >> 2)) * DIM + u8;
  const unsigned short* bSrc = Bt + (size_t)(n0 + (tid >> 2)) * DIM + u8;

  // ds_read byte offsets within a slot (sx = permuted 16-B slot select)
  const int sx = ((lq ^ ((rm >> 1) & 3)) << 4);
  const int aOff = (wm * 128 + rm) * 64 + sx;            // + fr*1024
  const int bOff = 16384 + (wn * 64 + rm) * 64 + sx;     // + nf*1024

#define STAGE(slot, kt) do { \
    char* _b = lds + (slot) * 32768 + wid * 1024; \
    __builtin_amdgcn_global_load_lds((const AS1 void*)(aSrc + (kt)),             (AS3 void*)(_b),         16, 0, 0); \
    __builtin_amdgcn_global_load_lds((const AS1 void*)(aSrc + (kt) + 128 * DIM), (AS3 void*)(_b + 8192),  16, 0, 0); \
    __builtin_amdgcn_global_load_lds((const AS1 void*)(bSrc + (kt)),             (AS3 void*)(_b + 16384), 16, 0, 0); \
    __builtin_amdgcn_global_load_lds((const AS1 void*)(bSrc + (kt) + 128 * DIM), (AS3 void*)(_b + 24576), 16, 0, 0); \
  } while (0)

#define COMPUTE(slot) do { \
    const char* _sb = lds + (slot) * 32768; \
    v8bf _a[8], _bv[4]; \
    _Pragma("unroll") for (int fr = 0; fr < 8; ++fr) _a[fr] = *(const v8bf*)(_sb + aOff + fr * 1024); \
    _Pragma("unroll") for (int nf = 0; nf < 4; ++nf) _bv[nf] = *(const v8bf*)(_sb + bOff + nf * 1024); \
    __builtin_amdgcn_s_setprio(1); \
    _Pragma("unroll") for (int fr = 0; fr < 8; ++fr) \
      _Pragma("unroll") for (int nf = 0; nf < 4; ++nf) \
        acc[fr][nf] = __builtin_amdgcn_mfma_f32_16x16x32_bf16(_a[fr], _bv[nf], acc[fr][nf], 0, 0, 0); \
    __builtin_amdgcn_s_setprio(0); \
  } while (0)

  // prologue: tiles 0,1,2 in flight (12 loads)
  STAGE(0, 0);
  STAGE(1, 32);
  STAGE(2, 64);

  // main loop: 29 iterations, steady-state 16 loads in flight, wait to 12
  for (int t = 0; t < 29; ++t) {
    STAGE((t + 3) & 3, (t + 3) * 32);
    asm volatile("s_waitcnt vmcnt(12)\n\ts_barrier" ::: "memory");
    COMPUTE(t & 3);
    asm volatile("s_barrier" ::: "memory");
  }
  // tail: tiles 29,30,31 (no more stages; drain 8 -> 4 -> 0)
  asm volatile("s_waitcnt vmcnt(8)\n\ts_barrier" ::: "memory");
  COMPUTE(1);
  asm volatile("s_barrier" ::: "memory");
  asm volatile("s_waitcnt vmcnt(4)\n\ts_barrier" ::: "memory");
  COMPUTE(2);
  asm volatile("s_barrier" ::: "memory");
  asm volatile("s_waitcnt vmcnt(0)\n\ts_barrier" ::: "memory");
  COMPUTE(3);

  // ---- epilogue ----
  // C/D layout (verified m89/m91): n = rm, m = lq*4 + reg
  const int mr = lq * 4;
  float rmax[8][4];
#pragma unroll
  for (int fr = 0; fr < 8; ++fr) {
#pragma unroll
    for (int r = 0; r < 4; ++r) {
      float mx = acc[fr][0][r];
#pragma unroll
      for (int nf = 1; nf < 4; ++nf) mx = fmaxf(mx, acc[fr][nf][r]);
      rmax[fr][r] = mx;
    }
#pragma unroll
    for (int nf = 0; nf < 4; ++nf) {
      const int mrow = m0 + wm * 128 + fr * 16 + mr;
      const int ncol = n0 + wn * 64 + nf * 16 + rm;
#pragma unroll
      for (int r = 0; r < 4; ++r)
        Lg[(size_t)(mrow + r) * NKN + ncol] = f2bf(acc[fr][nf][r]);
    }
  }
  // reduce row-max across the 16 rm lanes (xor<16 stays within the group)
#pragma unroll
  for (int fr = 0; fr < 8; ++fr)
#pragma unroll
    for (int r = 0; r < 4; ++r) {
#pragma unroll
      for (int off = 1; off < 16; off <<= 1)
        rmax[fr][r] = fmaxf(rmax[fr][r], __shfl_xor(rmax[fr][r], off));
    }
  // cross-wave (wn) reduce via LDS; smax region = ring slot 0 (last read at
  // t=28, all reads retired before the end-of-28 barrier -> safe to reuse)
  float* smax = (float*)lds;  // [4][256]
  if (rm == 0) {
#pragma unroll
    for (int fr = 0; fr < 8; ++fr)
#pragma unroll
      for (int r = 0; r < 4; ++r)
        smax[wn * 256 + wm * 128 + fr * 16 + mr + r] = rmax[fr][r];
  }
  __syncthreads();
  if (tid < 256) {
    float v = fmaxf(fmaxf(smax[tid], smax[256 + tid]),
                    fmaxf(smax[512 + tid], smax[768 + tid]));
    CmaxT[(size_t)nb * TOK + m0 + tid] = bf2key(f2bf(v));
  }
#undef STAGE
#undef COMPUTE
}

// ---------------------------------------------------------------------------
// K3: per-token candidate pick from chunk maxes (CmaxT layout [NCHUNK][TOK]).
// tau = 32nd-largest chunk-max key; collect all entries with key>>4 >= tau>>4
// (superset of true top-32: every top-32 element >= tau). Reads only
// qualifying 256-col chunks.
// ---------------------------------------------------------------------------
__global__ __launch_bounds__(256) void k_pick(const unsigned short* __restrict__ CmaxT,
                                              const unsigned short* __restrict__ Lg,
                                              int* __restrict__ cidx,
                                              int* __restrict__ ccnt) {
  __shared__ unsigned short keys[NCHUNK];
  __shared__ int qlist[NCHUNK];
  __shared__ int qn, scnt, bsS;
  const int t = blockIdx.x, tid = threadIdx.x;
  const int lane = tid & 63, w = tid >> 6;
  keys[tid] = CmaxT[(size_t)tid * TOK + t];
  if (tid == 0) { qn = 0; scnt = 0; }
  __syncthreads();
  if (w == 0) {
    int v[4];
#pragma unroll
    for (int j = 0; j < 4; j++) v[j] = keys[lane * 4 + j];
    int t32 = 0;
    for (int it = 0; it < 32; it++) {
      int lm = v[0];
#pragma unroll
      for (int j = 1; j < 4; j++) lm = max(lm, v[j]);
      int gm = lm;
#pragma unroll
      for (int off = 32; off > 0; off >>= 1) gm = max(gm, __shfl_xor(gm, off));
      unsigned long long msk = __ballot(lm == gm);
      if (lane == __ffsll((long long)msk) - 1) {
        bool done = false;
#pragma unroll
        for (int j = 0; j < 4; j++)
          if (!done && v[j] == gm) { v[j] = -1; done = true; }
      }
      t32 = gm;
    }
    if (lane == 0) bsS = t32 >> 4;
  }
  __syncthreads();
  const int bs = bsS;
  if ((keys[tid] >> 4) >= bs) { int p = atomicAdd(&qn, 1); qlist[p] = tid; }
  __syncthreads();
  const int nq = qn;
  for (int qi = 0; qi < nq; qi++) {
    const int col = qlist[qi] * 256 + tid;
    unsigned short key = bf2key(Lg[(size_t)t * NKN + col]);
    if ((int)(key >> 4) >= bs) {
      int p = atomicAdd(&scnt, 1);
      if (p < CAP) cidx[(size_t)t * CAP + p] = col;
    }
  }
  __syncthreads();
  if (tid == 0) ccnt[t] = min(scnt, CAP);
}

// ---------------------------------------------------------------------------
// K4: exact fp64 rescore of candidates + exact top-20 selection
// ---------------------------------------------------------------------------
__global__ __launch_bounds__(256) void k_rescore(const float* __restrict__ x,
                                                 const float* __restrict__ WT,
                                                 const int* __restrict__ cidx,
                                                 const int* __restrict__ ccnt,
                                                 int* __restrict__ coarse) {
  __shared__ float xs[DIM];
  __shared__ double sc[CAP];
  __shared__ int ci[CAP];
  const int t = blockIdx.x, tid = threadIdx.x;
  const int lane = tid & 63, w = tid >> 6;
  const int cnt = ccnt[t];
  for (int i = tid; i < DIM; i += 256) xs[i] = x[(size_t)t * DIM + i];
  for (int i = tid; i < CAP; i += 256) {
    sc[i] = -1e300;
    ci[i] = (i < cnt) ? cidx[(size_t)t * CAP + i] : 0;
  }
  __syncthreads();
  for (int c = w; c < cnt; c += 4) {
    const float* wr = WT + (size_t)ci[c] * DIM;
    double sacc = 0.0;
#pragma unroll 4
    for (int i = lane; i < DIM; i += 64) sacc += (double)xs[i] * (double)wr[i];
#pragma unroll
    for (int off = 32; off > 0; off >>= 1) sacc += __shfl_down(sacc, off);
    if (lane == 0) sc[c] = sacc;
  }
  __syncthreads();
  if (w == 0) {
    double v[4];
    int ix[4];
#pragma unroll
    for (int j = 0; j < 4; j++) { v[j] = sc[lane + j * 64]; ix[j] = lane + j * 64; }
    for (int kk = 0; kk < CK; kk++) {
      double v1 = v[0]; int i1 = ix[0];
#pragma unroll
      for (int j = 1; j < 4; j++)
        if (v[j] > v1) { v1 = v[j]; i1 = ix[j]; }
#pragma unroll
      for (int off = 32; off > 0; off >>= 1) {
        double ov = __shfl_down(v1, off);
        int oi = __shfl_down(i1, off);
        if (ov > v1) { v1 = ov; i1 = oi; }
      }
      i1 = __shfl(i1, 0);
      if (lane == 0) coarse[(size_t)t * CK + kk] = ci[i1];
#pragma unroll
      for (int j = 0; j < 4; j++)
        if (i1 == ix[j]) v[j] = -1e300;
    }
  }
}

// ---------------------------------------------------------------------------
// K5: query = x @ W_enc
// ---------------------------------------------------------------------------
__global__ __launch_bounds__(128) void k_query(const float* __restrict__ x,
                                               const float* __restrict__ Wenc,
                                               float* __restrict__ q) {
  const int j = threadIdx.x;
  const int t0 = blockIdx.x * 4;
  float s0 = 0.f, s1 = 0.f, s2 = 0.f, s3 = 0.f;
  const float* x0 = x + (size_t)t0 * DIM;
  for (int d = 0; d < DIM; d++) {
    float wv = Wenc[d * RNK + j];
    s0 = fmaf(x0[d], wv, s0);
    s1 = fmaf(x0[DIM + d], wv, s1);
    s2 = fmaf(x0[2 * DIM + d], wv, s2);
    s3 = fmaf(x0[3 * DIM + d], wv, s3);
  }
  q[(size_t)t0 * RNK + j] = s0;
  q[(size_t)(t0 + 1) * RNK + j] = s1;
  q[(size_t)(t0 + 2) * RNK + j] = s2;
  q[(size_t)(t0 + 3) * RNK + j] = s3;
}

// ---------------------------------------------------------------------------
// K6: fine scores vs 20 candidates, top-10, softmax, weighted V blend
// ---------------------------------------------------------------------------
__global__ __launch_bounds__(256) void k_fine(const float* __restrict__ q,
                                              const float* __restrict__ Kall,
                                              const float* __restrict__ Vall,
                                              const int* __restrict__ coarse,
                                              float* __restrict__ out) {
  __shared__ float qs[RNK];
  __shared__ float fsc[CK];
  __shared__ int gix[CK];
  __shared__ float wts[FK];
  __shared__ int fidx[FK];
  const int t = blockIdx.x, tid = threadIdx.x;
  const int lane = tid & 63, w = tid >> 6;
  if (tid < RNK) qs[tid] = q[(size_t)t * RNK + tid];
  if (tid < CK) gix[tid] = coarse[(size_t)t * CK + tid];
  __syncthreads();
  for (int c = w; c < CK; c += 4) {
    const float* kr = Kall + (size_t)gix[c] * RNK;
    float s = 0.f;
    s = fmaf(qs[lane], kr[lane], s);
    s = fmaf(qs[lane + 64], kr[lane + 64], s);
#pragma unroll
    for (int off = 32; off > 0; off >>= 1) s += __shfl_down(s, off);
    if (lane == 0) fsc[c] = s * 0.08838834764831843f;  // 1/sqrt(128)
  }
  __syncthreads();
  if (w == 0) {
    float vv = (lane < CK) ? fsc[lane] : -3e38f;
    float myv = -3e38f; int myp = 0;
    for (int kk = 0; kk < FK; kk++) {
      float v1 = vv; int p1 = lane;
#pragma unroll
      for (int off = 32; off > 0; off >>= 1) {
        float ov = __shfl_down(v1, off);
        int op = __shfl_down(p1, off);
        if (ov > v1) { v1 = ov; p1 = op; }
      }
      v1 = __shfl(v1, 0); p1 = __shfl(p1, 0);
      if (lane == kk) { myv = v1; myp = p1; }
      if (lane == p1) vv = -3e38f;
    }
    float sv = (lane < FK) ? myv : -3e38f;
    float mx = sv;
#pragma unroll
    for (int off = 8; off > 0; off >>= 1) mx = fmaxf(mx, __shfl_xor(mx, off, 16));
    float e = (lane < FK) ? expf(sv - mx) : 0.f;
    float se = e;
#pragma unroll
    for (int off = 8; off > 0; off >>= 1) se += __shfl_xor(se, off, 16);
    if (lane < FK) { wts[lane] = e / se; fidx[lane] = gix[myp]; }
  }
  __syncthreads();
  float4 a = make_float4(0.f, 0.f, 0.f, 0.f);
#pragma unroll
  for (int f = 0; f < FK; f++) {
    const float wt = wts[f];
    const float4 v = *reinterpret_cast<const float4*>(&Vall[(size_t)fidx[f] * DIM + tid * 4]);
    a.x = fmaf(wt, v.x, a.x);
    a.y = fmaf(wt, v.y, a.y);
    a.z = fmaf(wt, v.z, a.z);
    a.w = fmaf(wt, v.w, a.w);
  }
  *reinterpret_cast<float4*>(&out[(size_t)t * DIM + tid * 4]) = a;
}

// ---------------------------------------------------------------------------

extern "C" void kernel_launch(void* const* d_in, const int* in_sizes, int n_in,
                              void* d_out, int out_size, void* d_ws, size_t ws_size,
                              hipStream_t stream) {
  const float* x = (const float*)d_in[0];      // [4096][1024]
  const float* Wr = (const float*)d_in[1];     // [1024][65536]
  const float* Wenc = (const float*)d_in[2];   // [1024][128]
  const float* Kall = (const float*)d_in[3];   // [65536][128]
  const float* Vall = (const float*)d_in[4];   // [65536][1024]
  float* out = (float*)d_out;                  // [4096][1024]

  char* ws = (char*)d_ws;
  constexpr size_t OFF_WT = 0;                  // fp32 W^T    256 MB (live until rescore)
  constexpr size_t OFF_WTB = 268435456;         // bf16 W^T    128 MB (dead after gemm)
  constexpr size_t OFF_XB = 402653184;          // bf16 x        8 MB (dead after gemm)
  constexpr size_t OFF_LG = 411041792;          // bf16 logits 512 MB
  constexpr size_t OFF_CMAX = 947912704;        // chunk-max keys 2 MB (4 MB reserved)
  float* WT = (float*)(ws + OFF_WT);
  unsigned short* WTb = (unsigned short*)(ws + OFF_WTB);
  unsigned short* xb = (unsigned short*)(ws + OFF_XB);
  unsigned short* Lg = (unsigned short*)(ws + OFF_LG);
  unsigned short* CmaxT = (unsigned short*)(ws + OFF_CMAX);
  // aliases into regions that are dead after k_gemm:
  int* cidx = (int*)(ws + OFF_XB);                        // 4 MB
  int* ccnt = (int*)(ws + OFF_XB + 4194304);              // 16 KB
  int* coarse = (int*)(ws + OFF_XB + 4259840);            // 320 KB
  float* q = (float*)(ws + OFF_WTB);                      // 2 MB

  k_transpose<<<65536, 256, 0, stream>>>(Wr, WT, WTb);
  k_cvt_x<<<4096, 256, 0, stream>>>(x, xb);
  k_gemm<<<4096, 512, 0, stream>>>(xb, WTb, Lg, CmaxT);
  k_pick<<<4096, 256, 0, stream>>>(CmaxT, Lg, cidx, ccnt);
  k_rescore<<<4096, 256, 0, stream>>>(x, WT, cidx, ccnt, coarse);
  k_query<<<1024, 128, 0, stream>>>(x, Wenc, q);
  k_fine<<<4096, 256, 0, stream>>>(q, Kall, Vall, coarse, out);
}

// Round 5
// 1200.730 us; speedup vs baseline: 1.5338x; 1.0210x over previous
//
#include <hip/hip_runtime.h>

#define DIM 1024
#define NKN 65536
#define TOK 4096
#define CK 20
#define FK 10
#define RNK 128
#define CAP 256
#define NCHUNK 256   // 65536 / 256 cols per GEMM block

typedef __bf16 v8bf __attribute__((ext_vector_type(8)));
typedef float v4f __attribute__((ext_vector_type(4)));

#define AS1 __attribute__((address_space(1)))
#define AS3 __attribute__((address_space(3)))

__device__ __forceinline__ unsigned short f2bf(float f) {
  // round-to-nearest-even fp32 -> bf16 (finite inputs only)
  unsigned u = __builtin_bit_cast(unsigned, f);
  u += 0x7FFFu + ((u >> 16) & 1u);
  return (unsigned short)(u >> 16);
}
__device__ __forceinline__ unsigned short bf2key(unsigned short b) {
  // monotone order-preserving key for bf16 bits
  return (b & 0x8000) ? (unsigned short)(~b) : (unsigned short)(b | 0x8000);
}

// ---------------------------------------------------------------------------
// K1: transpose W_router [DIM][NKN] -> WT fp32 [NKN][DIM] and WT bf16 [NKN][DIM]
// ---------------------------------------------------------------------------
__global__ __launch_bounds__(256) void k_transpose(const float* __restrict__ W,
                                                   float* __restrict__ WT,
                                                   unsigned short* __restrict__ WTb) {
  __shared__ float tile[32][33];
  const int n0 = (blockIdx.x & 2047) << 5;
  const int d0 = (blockIdx.x >> 11) << 5;
  const int c = threadIdx.x & 31, r0 = threadIdx.x >> 5;
#pragma unroll
  for (int i = 0; i < 4; i++) {
    int r = r0 + i * 8;
    tile[r][c] = W[(size_t)(d0 + r) * NKN + n0 + c];
  }
  __syncthreads();
#pragma unroll
  for (int i = 0; i < 4; i++) {
    int r = r0 + i * 8;
    float v = tile[c][r];  // = W[d0+c][n0+r]
    size_t o = (size_t)(n0 + r) * DIM + d0 + c;
    WT[o] = v;
    WTb[o] = f2bf(v);
  }
}

// ---------------------------------------------------------------------------
// K1b: convert x fp32 -> bf16
// ---------------------------------------------------------------------------
__global__ __launch_bounds__(256) void k_cvt_x(const float* __restrict__ x,
                                               unsigned short* __restrict__ xb) {
  const int i = blockIdx.x * 256 + threadIdx.x;
  const float4 v = reinterpret_cast<const float4*>(x)[i];
  ushort4 o;
  o.x = f2bf(v.x); o.y = f2bf(v.y); o.z = f2bf(v.z); o.w = f2bf(v.w);
  reinterpret_cast<ushort4*>(xb)[i] = o;
}

// ---------------------------------------------------------------------------
// K2: deep-pipelined bf16 MFMA GEMM (T3+T4+T5), 4 phases per K-tile.
// 256x256 tile, BK=32, 512 threads = 8 waves (2M x 4N), per-wave C = 128x64.
// LDS = 4-slot ring (4 x 32 KiB), prefetch distance 3 K-tiles.
// Per phase: {2 A-frag ds_reads (+4 B in phase 1) | 1 gload_lds stage round |
// barrier | setprio(1) 8 MFMA setprio(0) | barrier} -- the m196/m218 fine
// interleave that creates wave role-split. vmcnt counted once per tile at
// tile top: steady-state vmcnt(8) (= tiles t+1,t+2 in flight), drains 8/4/0.
// Ring safety: tile t reads slot t&3; stages during tile t write slot
// (t+3)&3 (distinct mod 4); tile-top vmcnt+barrier orders the handoff.
// LDS layout: 64-B rows, 4 x 16-B slots, phys slot = logical ^ stuff; per
// 16-lane group each bank hit exactly 2x (free). Rule-21: linear gload_lds
// dest + inverse-permuted global src + same permutation on ds_read.
// ---------------------------------------------------------------------------
__global__ __launch_bounds__(512, 2) void k_gemm(const unsigned short* __restrict__ A,
                                                 const unsigned short* __restrict__ Bt,
                                                 unsigned short* __restrict__ Lg,
                                                 unsigned short* __restrict__ CmaxT) {
  __shared__ __align__(16) char lds[131072];  // ring[4]: {A 16 KB, B 16 KB}
  const int tid = threadIdx.x;
  const int lane = tid & 63, wid = tid >> 6;
  const int wm = wid >> 2, wn = wid & 3;
  const int mb = blockIdx.x & 15, nb = blockIdx.x >> 4;  // m-fast: B-panel reuse
  const int m0 = mb << 8, n0 = nb << 8;
  const int rm = lane & 15, lq = lane >> 4;
  v4f acc[8][4] = {};

  // staging source (inverse-permuted): thread covers phys row tid>>2, slot tid&3
  const int u8 = (((tid & 3) ^ ((tid >> 3) & 3)) << 3);
  const unsigned short* aSrc = A + (size_t)(m0 + (tid >> 2)) * DIM + u8;
  const unsigned short* bSrc = Bt + (size_t)(n0 + (tid >> 2)) * DIM + u8;

  // ds_read byte offsets within a slot (sx = permuted 16-B slot select)
  const int sx = ((lq ^ ((rm >> 1) & 3)) << 4);
  const int aOff = (wm * 128 + rm) * 64 + sx;            // + fr*1024
  const int bOff = 16384 + (wn * 64 + rm) * 64 + sx;     // + nf*1024

  // prologue: stage tiles 0,1,2 (12 loads in flight)
#pragma unroll
  for (int tt = 0; tt < 3; ++tt) {
    char* base = lds + tt * 32768 + wid * 1024;
    const unsigned short* as = aSrc + tt * 32;
    const unsigned short* bs = bSrc + tt * 32;
    __builtin_amdgcn_global_load_lds((const AS1 void*)as, (AS3 void*)base, 16, 0, 0);
    __builtin_amdgcn_global_load_lds((const AS1 void*)(as + 128 * DIM), (AS3 void*)(base + 8192), 16, 0, 0);
    __builtin_amdgcn_global_load_lds((const AS1 void*)bs, (AS3 void*)(base + 16384), 16, 0, 0);
    __builtin_amdgcn_global_load_lds((const AS1 void*)(bs + 128 * DIM), (AS3 void*)(base + 24576), 16, 0, 0);
  }

#define MM(FR, AREG) \
  acc[FR][0] = __builtin_amdgcn_mfma_f32_16x16x32_bf16(AREG, b0, acc[FR][0], 0, 0, 0); \
  acc[FR][1] = __builtin_amdgcn_mfma_f32_16x16x32_bf16(AREG, b1, acc[FR][1], 0, 0, 0); \
  acc[FR][2] = __builtin_amdgcn_mfma_f32_16x16x32_bf16(AREG, b2, acc[FR][2], 0, 0, 0); \
  acc[FR][3] = __builtin_amdgcn_mfma_f32_16x16x32_bf16(AREG, b3, acc[FR][3], 0, 0, 0);

#define TILE(T, VM, DOSTAGE) do { \
    asm volatile("s_waitcnt vmcnt(" VM ")" ::: "memory"); \
    __builtin_amdgcn_s_barrier(); \
    const char* sb = lds + ((T) & 3) * 32768; \
    char* stb = lds + (((T) + 3) & 3) * 32768 + wid * 1024; \
    const unsigned short* sa = aSrc + ((T) + 3) * 32; \
    const unsigned short* sg = bSrc + ((T) + 3) * 32; \
    /* phase 1 */ \
    v8bf b0 = *(const v8bf*)(sb + bOff); \
    v8bf b1 = *(const v8bf*)(sb + bOff + 1024); \
    v8bf b2 = *(const v8bf*)(sb + bOff + 2048); \
    v8bf b3 = *(const v8bf*)(sb + bOff + 3072); \
    v8bf a0 = *(const v8bf*)(sb + aOff); \
    v8bf a1 = *(const v8bf*)(sb + aOff + 1024); \
    if (DOSTAGE) __builtin_amdgcn_global_load_lds((const AS1 void*)sa, (AS3 void*)stb, 16, 0, 0); \
    __builtin_amdgcn_s_barrier(); \
    __builtin_amdgcn_s_setprio(1); MM(0, a0) MM(1, a1) __builtin_amdgcn_s_setprio(0); \
    __builtin_amdgcn_s_barrier(); \
    /* phase 2 */ \
    a0 = *(const v8bf*)(sb + aOff + 2048); \
    a1 = *(const v8bf*)(sb + aOff + 3072); \
    if (DOSTAGE) __builtin_amdgcn_global_load_lds((const AS1 void*)(sa + 128 * DIM), (AS3 void*)(stb + 8192), 16, 0, 0); \
    __builtin_amdgcn_s_barrier(); \
    __builtin_amdgcn_s_setprio(1); MM(2, a0) MM(3, a1) __builtin_amdgcn_s_setprio(0); \
    __builtin_amdgcn_s_barrier(); \
    /* phase 3 */ \
    a0 = *(const v8bf*)(sb + aOff + 4096); \
    a1 = *(const v8bf*)(sb + aOff + 5120); \
    if (DOSTAGE) __builtin_amdgcn_global_load_lds((const AS1 void*)sg, (AS3 void*)(stb + 16384), 16, 0, 0); \
    __builtin_amdgcn_s_barrier(); \
    __builtin_amdgcn_s_setprio(1); MM(4, a0) MM(5, a1) __builtin_amdgcn_s_setprio(0); \
    __builtin_amdgcn_s_barrier(); \
    /* phase 4 (trailing barrier = next tile's vmcnt+barrier) */ \
    a0 = *(const v8bf*)(sb + aOff + 6144); \
    a1 = *(const v8bf*)(sb + aOff + 7168); \
    if (DOSTAGE) __builtin_amdgcn_global_load_lds((const AS1 void*)(sg + 128 * DIM), (AS3 void*)(stb + 24576), 16, 0, 0); \
    __builtin_amdgcn_s_barrier(); \
    __builtin_amdgcn_s_setprio(1); MM(6, a0) MM(7, a1) __builtin_amdgcn_s_setprio(0); \
  } while (0)

  for (int t = 0; t < 30; ++t) {
    TILE(t, "8", (t < 29));
  }
  TILE(30, "4", false);
  TILE(31, "0", false);
#undef TILE
#undef MM

  // ---- epilogue ----
  // C/D layout (verified m89/m91): n = rm, m = lq*4 + reg
  const int mr = lq * 4;
  float rmax[8][4];
#pragma unroll
  for (int fr = 0; fr < 8; ++fr) {
#pragma unroll
    for (int r = 0; r < 4; ++r) {
      float mx = acc[fr][0][r];
#pragma unroll
      for (int nf = 1; nf < 4; ++nf) mx = fmaxf(mx, acc[fr][nf][r]);
      rmax[fr][r] = mx;
    }
#pragma unroll
    for (int nf = 0; nf < 4; ++nf) {
      const int mrow = m0 + wm * 128 + fr * 16 + mr;
      const int ncol = n0 + wn * 64 + nf * 16 + rm;
#pragma unroll
      for (int r = 0; r < 4; ++r)
        Lg[(size_t)(mrow + r) * NKN + ncol] = f2bf(acc[fr][nf][r]);
    }
  }
  // reduce row-max across the 16 rm lanes (xor<16 stays within the group)
#pragma unroll
  for (int fr = 0; fr < 8; ++fr)
#pragma unroll
    for (int r = 0; r < 4; ++r) {
#pragma unroll
      for (int off = 1; off < 16; off <<= 1)
        rmax[fr][r] = fmaxf(rmax[fr][r], __shfl_xor(rmax[fr][r], off));
    }
  // cross-wave (wn) reduce via LDS slot 0 (last read at tile 28; safe)
  float* smax = (float*)lds;  // [4][256]
  if (rm == 0) {
#pragma unroll
    for (int fr = 0; fr < 8; ++fr)
#pragma unroll
      for (int r = 0; r < 4; ++r)
        smax[wn * 256 + wm * 128 + fr * 16 + mr + r] = rmax[fr][r];
  }
  __syncthreads();
  if (tid < 256) {
    float v = fmaxf(fmaxf(smax[tid], smax[256 + tid]),
                    fmaxf(smax[512 + tid], smax[768 + tid]));
    CmaxT[(size_t)nb * TOK + m0 + tid] = bf2key(f2bf(v));
  }
}

// ---------------------------------------------------------------------------
// K3: per-token candidate pick from chunk maxes (CmaxT layout [NCHUNK][TOK]).
// tau = 32nd-largest chunk-max key; collect all entries with key>>4 >= tau>>4
// (superset of true top-32: every top-32 element >= tau). Reads only
// qualifying 256-col chunks.
// ---------------------------------------------------------------------------
__global__ __launch_bounds__(256) void k_pick(const unsigned short* __restrict__ CmaxT,
                                              const unsigned short* __restrict__ Lg,
                                              int* __restrict__ cidx,
                                              int* __restrict__ ccnt) {
  __shared__ unsigned short keys[NCHUNK];
  __shared__ int qlist[NCHUNK];
  __shared__ int qn, scnt, bsS;
  const int t = blockIdx.x, tid = threadIdx.x;
  const int lane = tid & 63, w = tid >> 6;
  keys[tid] = CmaxT[(size_t)tid * TOK + t];
  if (tid == 0) { qn = 0; scnt = 0; }
  __syncthreads();
  if (w == 0) {
    int v[4];
#pragma unroll
    for (int j = 0; j < 4; j++) v[j] = keys[lane * 4 + j];
    int t32 = 0;
    for (int it = 0; it < 32; it++) {
      int lm = v[0];
#pragma unroll
      for (int j = 1; j < 4; j++) lm = max(lm, v[j]);
      int gm = lm;
#pragma unroll
      for (int off = 32; off > 0; off >>= 1) gm = max(gm, __shfl_xor(gm, off));
      unsigned long long msk = __ballot(lm == gm);
      if (lane == __ffsll((long long)msk) - 1) {
        bool done = false;
#pragma unroll
        for (int j = 0; j < 4; j++)
          if (!done && v[j] == gm) { v[j] = -1; done = true; }
      }
      t32 = gm;
    }
    if (lane == 0) bsS = t32 >> 4;
  }
  __syncthreads();
  const int bs = bsS;
  if ((keys[tid] >> 4) >= bs) { int p = atomicAdd(&qn, 1); qlist[p] = tid; }
  __syncthreads();
  const int nq = qn;
  for (int qi = 0; qi < nq; qi++) {
    const int col = qlist[qi] * 256 + tid;
    unsigned short key = bf2key(Lg[(size_t)t * NKN + col]);
    if ((int)(key >> 4) >= bs) {
      int p = atomicAdd(&scnt, 1);
      if (p < CAP) cidx[(size_t)t * CAP + p] = col;
    }
  }
  __syncthreads();
  if (tid == 0) ccnt[t] = min(scnt, CAP);
}

// ---------------------------------------------------------------------------
// K4: exact fp64 rescore of candidates + exact top-20 selection
// ---------------------------------------------------------------------------
__global__ __launch_bounds__(256) void k_rescore(const float* __restrict__ x,
                                                 const float* __restrict__ WT,
                                                 const int* __restrict__ cidx,
                                                 const int* __restrict__ ccnt,
                                                 int* __restrict__ coarse) {
  __shared__ float xs[DIM];
  __shared__ double sc[CAP];
  __shared__ int ci[CAP];
  const int t = blockIdx.x, tid = threadIdx.x;
  const int lane = tid & 63, w = tid >> 6;
  const int cnt = ccnt[t];
  for (int i = tid; i < DIM; i += 256) xs[i] = x[(size_t)t * DIM + i];
  for (int i = tid; i < CAP; i += 256) {
    sc[i] = -1e300;
    ci[i] = (i < cnt) ? cidx[(size_t)t * CAP + i] : 0;
  }
  __syncthreads();
  for (int c = w; c < cnt; c += 4) {
    const float* wr = WT + (size_t)ci[c] * DIM;
    double sacc = 0.0;
#pragma unroll 4
    for (int i = lane; i < DIM; i += 64) sacc += (double)xs[i] * (double)wr[i];
#pragma unroll
    for (int off = 32; off > 0; off >>= 1) sacc += __shfl_down(sacc, off);
    if (lane == 0) sc[c] = sacc;
  }
  __syncthreads();
  if (w == 0) {
    double v[4];
    int ix[4];
#pragma unroll
    for (int j = 0; j < 4; j++) { v[j] = sc[lane + j * 64]; ix[j] = lane + j * 64; }
    for (int kk = 0; kk < CK; kk++) {
      double v1 = v[0]; int i1 = ix[0];
#pragma unroll
      for (int j = 1; j < 4; j++)
        if (v[j] > v1) { v1 = v[j]; i1 = ix[j]; }
#pragma unroll
      for (int off = 32; off > 0; off >>= 1) {
        double ov = __shfl_down(v1, off);
        int oi = __shfl_down(i1, off);
        if (ov > v1) { v1 = ov; i1 = oi; }
      }
      i1 = __shfl(i1, 0);
      if (lane == 0) coarse[(size_t)t * CK + kk] = ci[i1];
#pragma unroll
      for (int j = 0; j < 4; j++)
        if (i1 == ix[j]) v[j] = -1e300;
    }
  }
}

// ---------------------------------------------------------------------------
// K5: query = x @ W_enc
// ---------------------------------------------------------------------------
__global__ __launch_bounds__(128) void k_query(const float* __restrict__ x,
                                               const float* __restrict__ Wenc,
                                               float* __restrict__ q) {
  const int j = threadIdx.x;
  const int t0 = blockIdx.x * 4;
  float s0 = 0.f, s1 = 0.f, s2 = 0.f, s3 = 0.f;
  const float* x0 = x + (size_t)t0 * DIM;
  for (int d = 0; d < DIM; d++) {
    float wv = Wenc[d * RNK + j];
    s0 = fmaf(x0[d], wv, s0);
    s1 = fmaf(x0[DIM + d], wv, s1);
    s2 = fmaf(x0[2 * DIM + d], wv, s2);
    s3 = fmaf(x0[3 * DIM + d], wv, s3);
  }
  q[(size_t)t0 * RNK + j] = s0;
  q[(size_t)(t0 + 1) * RNK + j] = s1;
  q[(size_t)(t0 + 2) * RNK + j] = s2;
  q[(size_t)(t0 + 3) * RNK + j] = s3;
}

// ---------------------------------------------------------------------------
// K6: fine scores vs 20 candidates, top-10, softmax, weighted V blend
// ---------------------------------------------------------------------------
__global__ __launch_bounds__(256) void k_fine(const float* __restrict__ q,
                                              const float* __restrict__ Kall,
                                              const float* __restrict__ Vall,
                                              const int* __restrict__ coarse,
                                              float* __restrict__ out) {
  __shared__ float qs[RNK];
  __shared__ float fsc[CK];
  __shared__ int gix[CK];
  __shared__ float wts[FK];
  __shared__ int fidx[FK];
  const int t = blockIdx.x, tid = threadIdx.x;
  const int lane = tid & 63, w = tid >> 6;
  if (tid < RNK) qs[tid] = q[(size_t)t * RNK + tid];
  if (tid < CK) gix[tid] = coarse[(size_t)t * CK + tid];
  __syncthreads();
  for (int c = w; c < CK; c += 4) {
    const float* kr = Kall + (size_t)gix[c] * RNK;
    float s = 0.f;
    s = fmaf(qs[lane], kr[lane], s);
    s = fmaf(qs[lane + 64], kr[lane + 64], s);
#pragma unroll
    for (int off = 32; off > 0; off >>= 1) s += __shfl_down(s, off);
    if (lane == 0) fsc[c] = s * 0.08838834764831843f;  // 1/sqrt(128)
  }
  __syncthreads();
  if (w == 0) {
    float vv = (lane < CK) ? fsc[lane] : -3e38f;
    float myv = -3e38f; int myp = 0;
    for (int kk = 0; kk < FK; kk++) {
      float v1 = vv; int p1 = lane;
#pragma unroll
      for (int off = 32; off > 0; off >>= 1) {
        float ov = __shfl_down(v1, off);
        int op = __shfl_down(p1, off);
        if (ov > v1) { v1 = ov; p1 = op; }
      }
      v1 = __shfl(v1, 0); p1 = __shfl(p1, 0);
      if (lane == kk) { myv = v1; myp = p1; }
      if (lane == p1) vv = -3e38f;
    }
    float sv = (lane < FK) ? myv : -3e38f;
    float mx = sv;
#pragma unroll
    for (int off = 8; off > 0; off >>= 1) mx = fmaxf(mx, __shfl_xor(mx, off, 16));
    float e = (lane < FK) ? expf(sv - mx) : 0.f;
    float se = e;
#pragma unroll
    for (int off = 8; off > 0; off >>= 1) se += __shfl_xor(se, off, 16);
    if (lane < FK) { wts[lane] = e / se; fidx[lane] = gix[myp]; }
  }
  __syncthreads();
  float4 a = make_float4(0.f, 0.f, 0.f, 0.f);
#pragma unroll
  for (int f = 0; f < FK; f++) {
    const float wt = wts[f];
    const float4 v = *reinterpret_cast<const float4*>(&Vall[(size_t)fidx[f] * DIM + tid * 4]);
    a.x = fmaf(wt, v.x, a.x);
    a.y = fmaf(wt, v.y, a.y);
    a.z = fmaf(wt, v.z, a.z);
    a.w = fmaf(wt, v.w, a.w);
  }
  *reinterpret_cast<float4*>(&out[(size_t)t * DIM + tid * 4]) = a;
}

// ---------------------------------------------------------------------------

extern "C" void kernel_launch(void* const* d_in, const int* in_sizes, int n_in,
                              void* d_out, int out_size, void* d_ws, size_t ws_size,
                              hipStream_t stream) {
  const float* x = (const float*)d_in[0];      // [4096][1024]
  const float* Wr = (const float*)d_in[1];     // [1024][65536]
  const float* Wenc = (const float*)d_in[2];   // [1024][128]
  const float* Kall = (const float*)d_in[3];   // [65536][128]
  const float* Vall = (const float*)d_in[4];   // [65536][1024]
  float* out = (float*)d_out;                  // [4096][1024]

  char* ws = (char*)d_ws;
  constexpr size_t OFF_WT = 0;                  // fp32 W^T    256 MB (live until rescore)
  constexpr size_t OFF_WTB = 268435456;         // bf16 W^T    128 MB (dead after gemm)
  constexpr size_t OFF_XB = 402653184;          // bf16 x        8 MB (dead after gemm)
  constexpr size_t OFF_LG = 411041792;          // bf16 logits 512 MB
  constexpr size_t OFF_CMAX = 947912704;        // chunk-max keys 2 MB (4 MB reserved)
  float* WT = (float*)(ws + OFF_WT);
  unsigned short* WTb = (unsigned short*)(ws + OFF_WTB);
  unsigned short* xb = (unsigned short*)(ws + OFF_XB);
  unsigned short* Lg = (unsigned short*)(ws + OFF_LG);
  unsigned short* CmaxT = (unsigned short*)(ws + OFF_CMAX);
  // aliases into regions that are dead after k_gemm:
  int* cidx = (int*)(ws + OFF_XB);                        // 4 MB
  int* ccnt = (int*)(ws + OFF_XB + 4194304);              // 16 KB
  int* coarse = (int*)(ws + OFF_XB + 4259840);            // 320 KB
  float* q = (float*)(ws + OFF_WTB);                      // 2 MB

  k_transpose<<<65536, 256, 0, stream>>>(Wr, WT, WTb);
  k_cvt_x<<<4096, 256, 0, stream>>>(x, xb);
  k_gemm<<<4096, 512, 0, stream>>>(xb, WTb, Lg, CmaxT);
  k_pick<<<4096, 256, 0, stream>>>(CmaxT, Lg, cidx, ccnt);
  k_rescore<<<4096, 256, 0, stream>>>(x, WT, cidx, ccnt, coarse);
  k_query<<<1024, 128, 0, stream>>>(x, Wenc, q);
  k_fine<<<4096, 256, 0, stream>>>(q, Kall, Vall, coarse, out);
}